// Round 3
// baseline (41.449 us; speedup 1.0000x reference)
//
#include <hip/hip_runtime.h>

#define NB 2048
#define NC 16
#define ND 256
#define OUTW 353
#define THRED 0.8f

typedef short bf16x8 __attribute__((ext_vector_type(8)));
typedef float f32x4 __attribute__((ext_vector_type(4)));

__device__ __forceinline__ unsigned short f2bf(float x) {   // RNE
    unsigned int u = __float_as_uint(x);
    u += 0x7FFFu + ((u >> 16) & 1u);
    return (unsigned short)(u >> 16);
}

__device__ __forceinline__ bf16x8 cvt8(const float4& a, const float4& b) {
    bf16x8 r;
    r[0] = (short)f2bf(a.x); r[1] = (short)f2bf(a.y);
    r[2] = (short)f2bf(a.z); r[3] = (short)f2bf(a.w);
    r[4] = (short)f2bf(b.x); r[5] = (short)f2bf(b.y);
    r[6] = (short)f2bf(b.z); r[7] = (short)f2bf(b.w);
    return r;
}

// One wave per b. No LDS, no barriers. A/B fragments, norms, and the masked
// neighbor-mean all derive from one 16-float4 global read per tile per lane.
__global__ __launch_bounds__(256, 2) void fused_kernel(const float* __restrict__ e,
                                                       const int* __restrict__ nm,
                                                       float* __restrict__ out) {
    const int bid = blockIdx.x;
    const int sb  = (bid & 7) * 64 + (bid >> 3);   // XCD-chunked (512 % 8 == 0, bijective)
    const int w   = threadIdx.x >> 6;
    const int l   = threadIdx.x & 63;
    const int col = l & 15, hi = l >> 4;
    const int b   = sb * 4 + w;
    const int koff = hi * 8;

    // ---- cumulative 0/1 masks for this lane's row (= col) ----
    float nmv[6];
#pragma unroll
    for (int u = 0; u < 6; ++u) {
        int gb = b + u - 3;
        nmv[u] = (gb >= 0 && gb < NB) ? (float)nm[gb * NC + col] : 0.f;
    }
    float maskv[6];
    maskv[0] = nmv[2];                 // left k=1: nm[b-1]
    maskv[1] = nmv[2] * nmv[1];
    maskv[2] = maskv[1] * nmv[0];
    maskv[3] = nmv[3];                 // right k=1: nm[b]
    maskv[4] = nmv[3] * nmv[4];
    maskv[5] = maskv[4] * nmv[5];

    // ---- own tile: A-fragments + fp32 norm ----
    const float* rp0 = e + ((size_t)b * NC + col) * ND + koff;
    float4 s[16];
#pragma unroll
    for (int c = 0; c < 8; ++c) {
        s[2 * c]     = *reinterpret_cast<const float4*>(rp0 + c * 32);
        s[2 * c + 1] = *reinterpret_cast<const float4*>(rp0 + c * 32 + 4);
    }
    bf16x8 af[8];
    float ssq = 0.f;
#pragma unroll
    for (int c = 0; c < 8; ++c) {
        const float4 a = s[2 * c], bb = s[2 * c + 1];
        af[c] = cvt8(a, bb);
        ssq = fmaf(a.x, a.x, ssq);  ssq = fmaf(a.y, a.y, ssq);
        ssq = fmaf(a.z, a.z, ssq);  ssq = fmaf(a.w, a.w, ssq);
        ssq = fmaf(bb.x, bb.x, ssq); ssq = fmaf(bb.y, bb.y, ssq);
        ssq = fmaf(bb.z, bb.z, ssq); ssq = fmaf(bb.w, bb.w, ssq);
    }
    ssq += __shfl_xor(ssq, 16, 64);
    ssq += __shfl_xor(ssq, 32, 64);
    const float nrm_own = sqrtf(ssq);   // ||e[b, col]||, fp32-exact

    // ---- 6 neighbor tiles: MFMA sims + norms + masked neigh accumulation ----
    const int offs[6] = {-1, -2, -3, 1, 2, 3};
    f32x4 acc[6];
    float nbn[6];
    float nacc[64];
#pragma unroll
    for (int q = 0; q < 64; ++q) nacc[q] = 0.f;

#pragma unroll
    for (int p = 0; p < 6; ++p) {
        acc[p] = (f32x4){0.f, 0.f, 0.f, 0.f};
        nbn[p] = 0.f;
        const int gb = b + offs[p];
        if (gb >= 0 && gb < NB) {
            const float* rp = e + ((size_t)gb * NC + col) * ND + koff;
#pragma unroll
            for (int c = 0; c < 8; ++c) {
                s[2 * c]     = *reinterpret_cast<const float4*>(rp + c * 32);
                s[2 * c + 1] = *reinterpret_cast<const float4*>(rp + c * 32 + 4);
            }
            float sq = 0.f;
            const float m = maskv[p];
#pragma unroll
            for (int c = 0; c < 8; ++c) {
                const float4 a = s[2 * c], bb = s[2 * c + 1];
                bf16x8 bf = cvt8(a, bb);
                acc[p] = __builtin_amdgcn_mfma_f32_16x16x32_bf16(af[c], bf, acc[p], 0, 0, 0);
                sq = fmaf(a.x, a.x, sq);  sq = fmaf(a.y, a.y, sq);
                sq = fmaf(a.z, a.z, sq);  sq = fmaf(a.w, a.w, sq);
                sq = fmaf(bb.x, bb.x, sq); sq = fmaf(bb.y, bb.y, sq);
                sq = fmaf(bb.z, bb.z, sq); sq = fmaf(bb.w, bb.w, sq);
                nacc[c * 8 + 0] = fmaf(m, a.x,  nacc[c * 8 + 0]);
                nacc[c * 8 + 1] = fmaf(m, a.y,  nacc[c * 8 + 1]);
                nacc[c * 8 + 2] = fmaf(m, a.z,  nacc[c * 8 + 2]);
                nacc[c * 8 + 3] = fmaf(m, a.w,  nacc[c * 8 + 3]);
                nacc[c * 8 + 4] = fmaf(m, bb.x, nacc[c * 8 + 4]);
                nacc[c * 8 + 5] = fmaf(m, bb.y, nacc[c * 8 + 5]);
                nacc[c * 8 + 6] = fmaf(m, bb.z, nacc[c * 8 + 6]);
                nacc[c * 8 + 7] = fmaf(m, bb.w, nacc[c * 8 + 7]);
            }
            sq += __shfl_xor(sq, 16, 64);
            sq += __shfl_xor(sq, 32, 64);
            nbn[p] = sqrtf(sq);
        }
    }

    // ---- sim epilogue ----
    float na[4];
#pragma unroll
    for (int r = 0; r < 4; ++r) na[r] = __shfl(nrm_own, hi * 4 + r, 16);

    float sim[6][4];
    float rowsum[4] = {0.f, 0.f, 0.f, 0.f};
#pragma unroll
    for (int p = 0; p < 6; ++p) {
        const bool mv = (maskv[p] != 0.f);
#pragma unroll
        for (int r = 0; r < 4; ++r) {
            float qd = acc[p][r] / fmaxf(na[r] * nbn[p], 1e-8f);
            float sv = (mv && qd > THRED) ? fminf(qd, 1.f) : 0.f;
            sim[p][r] = sv;
            rowsum[r] += sv;
        }
    }
#pragma unroll
    for (int r = 0; r < 4; ++r) {
#pragma unroll
        for (int o = 1; o < 16; o <<= 1) rowsum[r] += __shfl_xor(rowsum[r], o, 16);
    }

#pragma unroll
    for (int r = 0; r < 4; ++r) {
        const float inv = 1.0f / fmaxf(rowsum[r] + 1.0f, 1e-12f);
        float* orow = out + (size_t)(b * NC + hi * 4 + r) * OUTW;
#pragma unroll
        for (int p = 0; p < 6; ++p) orow[ND + p * NC + col] = sim[p][r] * inv;
        if (col == 0) orow[ND + 96] = inv;
    }

    // ---- neighbor embedding: lane owns row `col`, k = koff + c*32 + e ----
    const float s6 = 1.0f / 6.0f;
    float* nrow = out + (size_t)(b * NC + col) * OUTW + koff;
#pragma unroll
    for (int c = 0; c < 8; ++c) {
#pragma unroll
        for (int ee = 0; ee < 8; ++ee)
            nrow[c * 32 + ee] = nacc[c * 8 + ee] * s6;
    }
}

extern "C" void kernel_launch(void* const* d_in, const int* in_sizes, int n_in,
                              void* d_out, int out_size, void* d_ws, size_t ws_size,
                              hipStream_t stream) {
    const float* e = (const float*)d_in[0];
    const int* nmv = (const int*)d_in[1];
    float* out     = (float*)d_out;
    fused_kernel<<<NB / 4, 256, 0, stream>>>(e, nmv, out);
}